// Round 1
// baseline (523.221 us; speedup 1.0000x reference)
//
#include <hip/hip_runtime.h>
#include <math.h>

#define B_ 8
#define N_ 4096
#define C_ 384
#define H_ 8
#define D_ 48
#define M_ (B_*N_)
#define EPSF 1e-6f

typedef __attribute__((ext_vector_type(8))) short bf16x8;
typedef __attribute__((ext_vector_type(4))) float f32x4;
typedef unsigned short u16;
typedef unsigned int u32;

#define MFMA16(a,b,c) __builtin_amdgcn_mfma_f32_16x16x32_bf16((a),(b),(c),0,0,0)

__device__ __forceinline__ float bf2f(u16 u){
  union { u32 i; float f; } x; x.i = ((u32)u)<<16; return x.f;
}
__device__ __forceinline__ u16 f2bf(float f){
  u32 x = __builtin_bit_cast(u32, f);
  u32 r = (x + 0x7fffu + ((x >> 16) & 1u)) >> 16;
  return (u16)r;
}
__device__ __forceinline__ void gll16(const void* g, void* l){
  __builtin_amdgcn_global_load_lds(
      (const __attribute__((address_space(1))) u32*)g,
      (__attribute__((address_space(3))) u32*)l, 16, 0, 0);
}

// ---------------- k0: pack weights to bf16 (QKVG interleaved per head) ----
__global__ __launch_bounds__(256) void k0_prep(
    const float* __restrict__ wq, const float* __restrict__ bq,
    const float* __restrict__ wk, const float* __restrict__ bk,
    const float* __restrict__ wv, const float* __restrict__ bv,
    const float* __restrict__ wg, const float* __restrict__ bg,
    const float* __restrict__ pw_w, const float* __restrict__ wo,
    u16* __restrict__ wpack, u16* __restrict__ pwb, u16* __restrict__ wob,
    float* __restrict__ bpack)
{
  int idx = blockIdx.x*256 + threadIdx.x;
  const int NW = 1536*384;
  if (idx < NW) {
    int r = idx / 384, c = idx - r*384;
    int h = r / 192, s = (r % 192)/48, d = r % 48;
    const float* w = (s==0)?wq:(s==1)?wk:(s==2)?wv:wg;
    wpack[idx] = f2bf(w[(h*48+d)*384 + c]);
    if (c==0){
      const float* b = (s==0)?bq:(s==1)?bk:(s==2)?bv:bg;
      bpack[r] = b[h*48+d];
    }
  } else if (idx < NW + 147456) {
    int j = idx - NW;
    pwb[j] = f2bf(pw_w[j]);
  } else if (idx < NW + 2*147456) {
    int j = idx - NW - 147456;
    wob[j] = f2bf(wo[j]);
  }
}

// ---------------- k1: depthwise 3x3 conv (+dw_b) -> t bf16 ----------------
__global__ __launch_bounds__(256) void k1_dw(
    const float* __restrict__ x, const float* __restrict__ dw_w,
    const float* __restrict__ dw_b, u16* __restrict__ t)
{
  int idx = blockIdx.x*256 + threadIdx.x;      // 32768*96
  int c4 = idx % 96, m = idx / 96;
  int b = m >> 12, n = m & 4095;
  int i = n >> 6, j = n & 63;
  int c0 = c4*4;
  float a0 = dw_b[c0], a1 = dw_b[c0+1], a2 = dw_b[c0+2], a3 = dw_b[c0+3];
  const float* xb = x + ((size_t)b<<12)*384;
  #pragma unroll
  for (int di=-1; di<=1; ++di){
    int ii = i+di; if ((unsigned)ii >= 64u) continue;
    #pragma unroll
    for (int dj=-1; dj<=1; ++dj){
      int jj = j+dj; if ((unsigned)jj >= 64u) continue;
      const float4 xv = *(const float4*)(xb + (size_t)((ii<<6)+jj)*384 + c0);
      int tap = (di+1)*3 + (dj+1);
      a0 = fmaf(xv.x, dw_w[(c0  )*9 + tap], a0);
      a1 = fmaf(xv.y, dw_w[(c0+1)*9 + tap], a1);
      a2 = fmaf(xv.z, dw_w[(c0+2)*9 + tap], a2);
      a3 = fmaf(xv.w, dw_w[(c0+3)*9 + tap], a3);
    }
  }
  ushort4 o; o.x=f2bf(a0); o.y=f2bf(a1); o.z=f2bf(a2); o.w=f2bf(a3);
  *(ushort4*)(t + (size_t)m*384 + c0) = o;
}

// ---------------- k2: xm = bf16( x + t @ pw^T + pw_b ) --------------------
__global__ __launch_bounds__(256) void k2_gemm_pw(
    const u16* __restrict__ t, const u16* __restrict__ pwb,
    const float* __restrict__ x, const float* __restrict__ pw_b,
    u16* __restrict__ xm)
{
  __shared__ __align__(16) u16 As[128*64];
  __shared__ __align__(16) u16 Bs[128*64];
  const int m0 = blockIdx.x * 128;
  const int n0 = blockIdx.y * 128;
  const int tid = threadIdx.x, w = tid>>6, l = tid&63;
  f32x4 acc[4][4];
  #pragma unroll
  for (int i=0;i<4;i++)
    #pragma unroll
    for (int j=0;j<4;j++) acc[i][j] = (f32x4){0.f,0.f,0.f,0.f};

  for (int k0=0; k0<384; k0+=64) {
    #pragma unroll
    for (int i=0;i<4;i++){
      int ch = w*4+i;
      int row = ch*8 + (l>>3);
      gll16((const char*)t   + ((size_t)(m0+row)*384 + k0)*2 + (l&7)*16, (char*)As + ch*1024);
      gll16((const char*)pwb + ((size_t)(n0+row)*384 + k0)*2 + (l&7)*16, (char*)Bs + ch*1024);
    }
    __syncthreads();
    const int wr = (w>>1)*64, wc = (w&1)*64;
    #pragma unroll
    for (int kk=0; kk<64; kk+=32){
      bf16x8 a[4], bb[4];
      #pragma unroll
      for (int i=0;i<4;i++) a[i]  = *(const bf16x8*)&As[(wr + i*16 + (l&15))*64 + kk + (l>>4)*8];
      #pragma unroll
      for (int j=0;j<4;j++) bb[j] = *(const bf16x8*)&Bs[(wc + j*16 + (l&15))*64 + kk + (l>>4)*8];
      #pragma unroll
      for (int i=0;i<4;i++)
        #pragma unroll
        for (int j=0;j<4;j++)
          acc[i][j] = MFMA16(a[i], bb[j], acc[i][j]);
    }
    __syncthreads();
  }
  const int wr=(w>>1)*64, wc=(w&1)*64;
  #pragma unroll
  for (int j=0;j<4;j++){
    int n = n0 + wc + j*16 + (l&15);
    float bias = pw_b[n];
    #pragma unroll
    for (int i=0;i<4;i++)
      #pragma unroll
      for (int r=0;r<4;r++){
        int m = m0 + wr + i*16 + (l>>4)*4 + r;
        float v = acc[i][j][r] + x[(size_t)m*384 + n] + bias;
        xm[(size_t)m*384 + n] = f2bf(v);
      }
  }
}

// ---------------- k3: fused QKVG GEMM + activations -----------------------
__global__ __launch_bounds__(256) void k3_gemm_qkvg(
    const u16* __restrict__ xm, const u16* __restrict__ wpack,
    const float* __restrict__ bpack, const float* __restrict__ temperature,
    u16* __restrict__ qh, u16* __restrict__ kh, u16* __restrict__ vh)
{
  __shared__ __align__(16) u16 As[128*64];   // 16KB
  __shared__ __align__(16) u16 Bs[192*64];   // 24KB
  const int m0 = blockIdx.x * 128;
  const int h  = blockIdx.y;
  const int tid = threadIdx.x, w = tid>>6, l = tid&63;
  f32x4 acc[2][12];
  #pragma unroll
  for (int i=0;i<2;i++)
    #pragma unroll
    for (int j=0;j<12;j++) acc[i][j] = (f32x4){0.f,0.f,0.f,0.f};

  for (int k0=0; k0<384; k0+=64){
    #pragma unroll
    for (int i=0;i<4;i++){
      int ch = w*4+i, row = ch*8 + (l>>3);
      gll16((const char*)xm + ((size_t)(m0+row)*384 + k0)*2 + (l&7)*16, (char*)As + ch*1024);
    }
    #pragma unroll
    for (int i=0;i<6;i++){
      int ch = w*6+i, row = ch*8 + (l>>3);
      gll16((const char*)wpack + ((size_t)(h*192+row)*384 + k0)*2 + (l&7)*16, (char*)Bs + ch*1024);
    }
    __syncthreads();
    const int rbase = w*32;
    #pragma unroll
    for (int kk=0; kk<64; kk+=32){
      bf16x8 a0 = *(const bf16x8*)&As[(rbase +      (l&15))*64 + kk + (l>>4)*8];
      bf16x8 a1 = *(const bf16x8*)&As[(rbase + 16 + (l&15))*64 + kk + (l>>4)*8];
      #pragma unroll
      for (int j=0;j<12;j++){
        bf16x8 bb = *(const bf16x8*)&Bs[(j*16 + (l&15))*64 + kk + (l>>4)*8];
        acc[0][j] = MFMA16(a0, bb, acc[0][j]);
        acc[1][j] = MFMA16(a1, bb, acc[1][j]);
      }
    }
    __syncthreads();
  }
  // epilogue: per-head phi(q*temp), phi(k), v*sigmoid(g)
  const float tq = temperature[h];
  const int b = m0 >> 12;
  const size_t bh = (size_t)b*8 + h;
  const int lc = l & 15;
  const int bb0 = h*192;
  float biasq[3], biask[3], biasv[3], biasg[3];
  #pragma unroll
  for (int j=0;j<3;j++){
    biasq[j] = bpack[bb0       + j*16 + lc];
    biask[j] = bpack[bb0 + 48  + j*16 + lc];
    biasv[j] = bpack[bb0 + 96  + j*16 + lc];
    biasg[j] = bpack[bb0 + 144 + j*16 + lc];
  }
  #pragma unroll
  for (int i=0;i<2;i++){
    #pragma unroll
    for (int r=0;r<4;r++){
      int m = m0 + w*32 + i*16 + (l>>4)*4 + r;
      int n = m & 4095;
      size_t rowq  = (bh*4096 + n)*64;
      size_t rowkv = (bh*4096 + n)*48;
      // q: temperature then phi (max over 48 channels = 3 frags x 16 lanes)
      float q0=(acc[i][0][r]+biasq[0])*tq;
      float q1=(acc[i][1][r]+biasq[1])*tq;
      float q2=(acc[i][2][r]+biasq[2])*tq;
      float mx = fmaxf(q0,fmaxf(q1,q2));
      mx = fmaxf(mx, __shfl_xor(mx,1,64));
      mx = fmaxf(mx, __shfl_xor(mx,2,64));
      mx = fmaxf(mx, __shfl_xor(mx,4,64));
      mx = fmaxf(mx, __shfl_xor(mx,8,64));
      qh[rowq +      lc] = f2bf(expf(q0-mx));
      qh[rowq + 16 + lc] = f2bf(expf(q1-mx));
      qh[rowq + 32 + lc] = f2bf(expf(q2-mx));
      qh[rowq + 48 + lc] = 0;                 // zero pad (K=64 for num GEMM)
      // k: phi
      float s0=acc[i][3][r]+biask[0];
      float s1=acc[i][4][r]+biask[1];
      float s2=acc[i][5][r]+biask[2];
      float mk = fmaxf(s0,fmaxf(s1,s2));
      mk = fmaxf(mk, __shfl_xor(mk,1,64));
      mk = fmaxf(mk, __shfl_xor(mk,2,64));
      mk = fmaxf(mk, __shfl_xor(mk,4,64));
      mk = fmaxf(mk, __shfl_xor(mk,8,64));
      kh[rowkv +      lc] = f2bf(expf(s0-mk));
      kh[rowkv + 16 + lc] = f2bf(expf(s1-mk));
      kh[rowkv + 32 + lc] = f2bf(expf(s2-mk));
      // v * sigmoid(g)
      #pragma unroll
      for (int j=0;j<3;j++){
        float vv = acc[i][6+j][r] + biasv[j];
        float gg = acc[i][9+j][r] + biasg[j];
        float sg = 1.f/(1.f + expf(-gg));
        vh[rowkv + j*16 + lc] = f2bf(vv*sg);
      }
    }
  }
}

// ---------------- k4: partial kv[d,e] and ksum[d] over N/4 ----------------
__global__ __launch_bounds__(256) void k4_kv(
    const u16* __restrict__ kh, const u16* __restrict__ vh,
    float* __restrict__ pkv, float* __restrict__ pks)
{
  __shared__ u16 kl[256*48];
  __shared__ u16 vl[256*48];
  const int bq = blockIdx.x;           // bh*4 + quarter
  const int bh = bq >> 2, qr = bq & 3;
  const int tid = threadIdx.x;
  const int d0 = (tid & 15)*3, e0 = (tid >> 4)*3;
  float a[3][3] = {};
  float ks[3] = {};
  const size_t base = ((size_t)bh*4096 + qr*1024)*48;
  for (int ch=0; ch<4; ++ch){
    __syncthreads();
    const uint4* gk = (const uint4*)(kh + base + (size_t)ch*256*48);
    const uint4* gv = (const uint4*)(vh + base + (size_t)ch*256*48);
    #pragma unroll
    for (int it=0; it<6; ++it){
      ((uint4*)kl)[it*256+tid] = gk[it*256+tid];
      ((uint4*)vl)[it*256+tid] = gv[it*256+tid];
    }
    __syncthreads();
    for (int n=0;n<256;++n){
      float k0=bf2f(kl[n*48+d0]), k1=bf2f(kl[n*48+d0+1]), k2=bf2f(kl[n*48+d0+2]);
      float v0=bf2f(vl[n*48+e0]), v1=bf2f(vl[n*48+e0+1]), v2=bf2f(vl[n*48+e0+2]);
      a[0][0]+=k0*v0; a[0][1]+=k0*v1; a[0][2]+=k0*v2;
      a[1][0]+=k1*v0; a[1][1]+=k1*v1; a[1][2]+=k1*v2;
      a[2][0]+=k2*v0; a[2][1]+=k2*v1; a[2][2]+=k2*v2;
      ks[0]+=k0; ks[1]+=k1; ks[2]+=k2;
    }
  }
  float* o = pkv + (size_t)bq*48*48;
  #pragma unroll
  for (int da=0;da<3;da++)
    #pragma unroll
    for (int eb=0;eb<3;eb++)
      o[(d0+da)*48 + e0+eb] = a[da][eb];
  if (tid < 16){
    pks[bq*48 + d0  ] = ks[0];
    pks[bq*48 + d0+1] = ks[1];
    pks[bq*48 + d0+2] = ks[2];
  }
}

// ---------------- k5: reduce partials -> kvp[e][d] bf16 (64x64, ksum row48)
__global__ __launch_bounds__(256) void k5_red(
    const float* __restrict__ pkv, const float* __restrict__ pks, u16* __restrict__ kvp)
{
  int bh = blockIdx.x, tid = threadIdx.x;
  for (int u=tid; u<4096; u+=256){
    int e = u >> 6, d = u & 63;
    float v = 0.f;
    if (e < 48 && d < 48){
      #pragma unroll
      for (int q=0;q<4;q++) v += pkv[(((size_t)bh*4+q)*48 + d)*48 + e];
    } else if (e == 48 && d < 48){
      #pragma unroll
      for (int q=0;q<4;q++) v += pks[((size_t)bh*4+q)*48 + d];
    }
    kvp[((size_t)bh*64 + e)*64 + d] = f2bf(v);
  }
}

// ---------------- k6: num/den -> a_hat bf16 [B,N,C] -----------------------
__global__ __launch_bounds__(256) void k6_num(
    const u16* __restrict__ qh, const u16* __restrict__ kvp, u16* __restrict__ ah)
{
  __shared__ __align__(16) u16 As[256*64]; // 32KB
  __shared__ __align__(16) u16 Bs[64*64];  // 8KB
  const int bh = blockIdx.x >> 4, nc = blockIdx.x & 15;
  const int tid = threadIdx.x, w = tid>>6, l = tid&63;
  const uint4* ga = (const uint4*)(qh + ((size_t)bh*4096 + nc*256)*64);
  #pragma unroll
  for (int it=0; it<8; ++it) ((uint4*)As)[it*256+tid] = ga[it*256+tid];
  const uint4* gb = (const uint4*)(kvp + (size_t)bh*4096);
  #pragma unroll
  for (int it=0; it<2; ++it) ((uint4*)Bs)[it*256+tid] = gb[it*256+tid];
  __syncthreads();
  f32x4 acc[4][4];
  #pragma unroll
  for (int i=0;i<4;i++)
    #pragma unroll
    for (int j=0;j<4;j++) acc[i][j] = (f32x4){0.f,0.f,0.f,0.f};
  const int rbase = w*64;
  #pragma unroll
  for (int kk=0; kk<64; kk+=32){
    bf16x8 a[4], bb[4];
    #pragma unroll
    for (int i=0;i<4;i++) a[i]  = *(const bf16x8*)&As[(rbase + i*16 + (l&15))*64 + kk + (l>>4)*8];
    #pragma unroll
    for (int j=0;j<4;j++) bb[j] = *(const bf16x8*)&Bs[(j*16 + (l&15))*64 + kk + (l>>4)*8];
    #pragma unroll
    for (int i=0;i<4;i++)
      #pragma unroll
      for (int j=0;j<4;j++)
        acc[i][j] = MFMA16(a[i], bb[j], acc[i][j]);
  }
  const int b = bh >> 3, h = bh & 7;
  #pragma unroll
  for (int i=0;i<4;i++){
    #pragma unroll
    for (int r=0;r<4;r++){
      float den = __shfl(acc[i][3][r], l & 48, 64) + EPSF;  // col 48 = q . ksum
      float rd = 1.f/den;
      int n = nc*256 + rbase + i*16 + (l>>4)*4 + r;
      size_t ob = ((size_t)b*4096 + n)*384 + h*48;
      ah[ob +      (l&15)] = f2bf(acc[i][0][r]*rd);
      ah[ob + 16 + (l&15)] = f2bf(acc[i][1][r]*rd);
      ah[ob + 32 + (l&15)] = f2bf(acc[i][2][r]*rd);
    }
  }
}

// ---------------- k7: out = a_hat @ wo^T + bo (fp32) ----------------------
__global__ __launch_bounds__(256) void k7_gemm_out(
    const u16* __restrict__ ah, const u16* __restrict__ wob,
    const float* __restrict__ bo, float* __restrict__ out)
{
  __shared__ __align__(16) u16 As[128*64];
  __shared__ __align__(16) u16 Bs[128*64];
  const int m0 = blockIdx.x * 128;
  const int n0 = blockIdx.y * 128;
  const int tid = threadIdx.x, w = tid>>6, l = tid&63;
  f32x4 acc[4][4];
  #pragma unroll
  for (int i=0;i<4;i++)
    #pragma unroll
    for (int j=0;j<4;j++) acc[i][j] = (f32x4){0.f,0.f,0.f,0.f};

  for (int k0=0; k0<384; k0+=64) {
    #pragma unroll
    for (int i=0;i<4;i++){
      int ch = w*4+i;
      int row = ch*8 + (l>>3);
      gll16((const char*)ah  + ((size_t)(m0+row)*384 + k0)*2 + (l&7)*16, (char*)As + ch*1024);
      gll16((const char*)wob + ((size_t)(n0+row)*384 + k0)*2 + (l&7)*16, (char*)Bs + ch*1024);
    }
    __syncthreads();
    const int wr = (w>>1)*64, wc = (w&1)*64;
    #pragma unroll
    for (int kk=0; kk<64; kk+=32){
      bf16x8 a[4], bb[4];
      #pragma unroll
      for (int i=0;i<4;i++) a[i]  = *(const bf16x8*)&As[(wr + i*16 + (l&15))*64 + kk + (l>>4)*8];
      #pragma unroll
      for (int j=0;j<4;j++) bb[j] = *(const bf16x8*)&Bs[(wc + j*16 + (l&15))*64 + kk + (l>>4)*8];
      #pragma unroll
      for (int i=0;i<4;i++)
        #pragma unroll
        for (int j=0;j<4;j++)
          acc[i][j] = MFMA16(a[i], bb[j], acc[i][j]);
    }
    __syncthreads();
  }
  const int wr=(w>>1)*64, wc=(w&1)*64;
  #pragma unroll
  for (int j=0;j<4;j++){
    int n = n0 + wc + j*16 + (l&15);
    float bias = bo[n];
    #pragma unroll
    for (int i=0;i<4;i++)
      #pragma unroll
      for (int r=0;r<4;r++){
        int m = m0 + wr + i*16 + (l>>4)*4 + r;
        out[(size_t)m*384 + n] = acc[i][j][r] + bias;
      }
  }
}

extern "C" void kernel_launch(void* const* d_in, const int* in_sizes, int n_in,
                              void* d_out, int out_size, void* d_ws, size_t ws_size,
                              hipStream_t stream)
{
  const float* x    = (const float*)d_in[0];
  const float* wq   = (const float*)d_in[1];
  const float* bq   = (const float*)d_in[2];
  const float* wk   = (const float*)d_in[3];
  const float* bk   = (const float*)d_in[4];
  const float* wv   = (const float*)d_in[5];
  const float* bv   = (const float*)d_in[6];
  const float* wg   = (const float*)d_in[7];
  const float* bg   = (const float*)d_in[8];
  const float* wo   = (const float*)d_in[9];
  const float* bo   = (const float*)d_in[10];
  const float* temp = (const float*)d_in[11];
  const float* dw_w = (const float*)d_in[12];
  const float* dw_b = (const float*)d_in[13];
  const float* pw_w = (const float*)d_in[14];
  const float* pw_b = (const float*)d_in[15];
  float* out = (float*)d_out;
  char* ws = (char*)d_ws;

  u16*   t     = (u16*)(ws + 0);            // 25165824 B ; reused as a_hat
  u16*   xm    = (u16*)(ws + 25165824);     // 25165824
  u16*   qh    = (u16*)(ws + 50331648);     // 33554432  [B,H,N,64]
  u16*   kh    = (u16*)(ws + 83886080);     // 25165824  [B,H,N,48]
  u16*   vh    = (u16*)(ws + 109051904);    // 25165824  [B,H,N,48]
  u16*   wpack = (u16*)(ws + 134217728);    // 1179648
  u16*   pwb   = (u16*)(ws + 135397376);    // 294912
  u16*   wob   = (u16*)(ws + 135692288);    // 294912
  float* bpack = (float*)(ws + 135987200);  // 6144
  float* pkv   = (float*)(ws + 135993344);  // 2359296
  float* pks   = (float*)(ws + 138352640);  // 49152
  u16*   kvp   = (u16*)(ws + 138401792);    // 524288

  k0_prep<<<3456, 256, 0, stream>>>(wq,bq,wk,bk,wv,bv,wg,bg,pw_w,wo, wpack,pwb,wob,bpack);
  k1_dw<<<12288, 256, 0, stream>>>(x, dw_w, dw_b, t);
  k2_gemm_pw<<<dim3(256,3), 256, 0, stream>>>(t, pwb, x, pw_b, xm);
  k3_gemm_qkvg<<<dim3(256,8), 256, 0, stream>>>(xm, wpack, bpack, temp, qh, kh, vh);
  k4_kv<<<256, 256, 0, stream>>>(kh, vh, pkv, pks);
  k5_red<<<64, 256, 0, stream>>>(pkv, pks, kvp);
  k6_num<<<1024, 256, 0, stream>>>(qh, kvp, t /*a_hat*/);
  k7_gemm_out<<<dim3(256,3), 256, 0, stream>>>(t, wob, bo, out);
}

// Round 3
// 294.027 us; speedup vs baseline: 1.7795x; 1.7795x over previous
//
#include <hip/hip_runtime.h>
#include <math.h>

#define EPSF 1e-6f

typedef __attribute__((ext_vector_type(8))) short bf16x8;
typedef __attribute__((ext_vector_type(4))) float f32x4;
typedef unsigned short u16;
typedef unsigned int u32;

#define MFMA16(a,b,c) __builtin_amdgcn_mfma_f32_16x16x32_bf16((a),(b),(c),0,0,0)

__device__ __forceinline__ float bf2f(u16 u){
  union { u32 i; float f; } x; x.i = ((u32)u)<<16; return x.f;
}
__device__ __forceinline__ u16 f2bf(float f){
  u32 x = __builtin_bit_cast(u32, f);
  u32 r = (x + 0x7fffu + ((x >> 16) & 1u)) >> 16;
  return (u16)r;
}
__device__ __forceinline__ void gll16(const void* g, void* l){
  __builtin_amdgcn_global_load_lds(
      (const __attribute__((address_space(1))) u32*)g,
      (__attribute__((address_space(3))) u32*)l, 16, 0, 0);
}

// ---------------- k0: pack weights to bf16 + zero kv accumulators ---------
__global__ __launch_bounds__(256) void k0_prep(
    const float* __restrict__ wq, const float* __restrict__ bq,
    const float* __restrict__ wk, const float* __restrict__ bk,
    const float* __restrict__ wv, const float* __restrict__ bv,
    const float* __restrict__ wg, const float* __restrict__ bg,
    const float* __restrict__ pw_w, const float* __restrict__ wo,
    u16* __restrict__ wpack, u16* __restrict__ pwb, u16* __restrict__ wob,
    float* __restrict__ bpack, float* __restrict__ kvacc, float* __restrict__ ksumacc)
{
  int idx = blockIdx.x*256 + threadIdx.x;
  const int NW = 1536*384;
  if (idx < NW) {
    int r = idx / 384, c = idx - r*384;
    int h = r / 192, s = (r % 192)/48, d = r % 48;
    const float* w = (s==0)?wq:(s==1)?wk:(s==2)?wv:wg;
    wpack[idx] = f2bf(w[(h*48+d)*384 + c]);
    if (c==0){
      const float* b = (s==0)?bq:(s==1)?bk:(s==2)?bv:bg;
      bpack[r] = b[h*48+d];
    }
  } else if (idx < NW + 147456) {
    pwb[idx - NW] = f2bf(pw_w[idx - NW]);
  } else if (idx < NW + 2*147456) {
    wob[idx - NW - 147456] = f2bf(wo[idx - NW - 147456]);
  } else if (idx < NW + 2*147456 + 147456) {
    kvacc[idx - NW - 2*147456] = 0.f;
  } else if (idx < NW + 2*147456 + 147456 + 3072) {
    ksumacc[idx - NW - 2*147456 - 147456] = 0.f;
  }
}

// ---------------- k1: depthwise 3x3 conv (+dw_b) -> t bf16 ----------------
__global__ __launch_bounds__(256) void k1_dw(
    const float* __restrict__ x, const float* __restrict__ dw_w,
    const float* __restrict__ dw_b, u16* __restrict__ t)
{
  int idx = blockIdx.x*256 + threadIdx.x;      // 32768*96
  int c4 = idx % 96, m = idx / 96;
  int b = m >> 12, n = m & 4095;
  int i = n >> 6, j = n & 63;
  int c0 = c4*4;
  float a0 = dw_b[c0], a1 = dw_b[c0+1], a2 = dw_b[c0+2], a3 = dw_b[c0+3];
  const float* xb = x + ((size_t)b<<12)*384;
  #pragma unroll
  for (int di=-1; di<=1; ++di){
    int ii = i+di; if ((unsigned)ii >= 64u) continue;
    #pragma unroll
    for (int dj=-1; dj<=1; ++dj){
      int jj = j+dj; if ((unsigned)jj >= 64u) continue;
      const float4 xv = *(const float4*)(xb + (size_t)((ii<<6)+jj)*384 + c0);
      int tap = (di+1)*3 + (dj+1);
      a0 = fmaf(xv.x, dw_w[(c0  )*9 + tap], a0);
      a1 = fmaf(xv.y, dw_w[(c0+1)*9 + tap], a1);
      a2 = fmaf(xv.z, dw_w[(c0+2)*9 + tap], a2);
      a3 = fmaf(xv.w, dw_w[(c0+3)*9 + tap], a3);
    }
  }
  ushort4 o; o.x=f2bf(a0); o.y=f2bf(a1); o.z=f2bf(a2); o.w=f2bf(a3);
  *(ushort4*)(t + (size_t)m*384 + c0) = o;
}

// ---------------- k2: xm = bf16( x + t @ pw^T + pw_b ) --------------------
__global__ __launch_bounds__(256) void k2_gemm_pw(
    const u16* __restrict__ t, const u16* __restrict__ pwb,
    const float* __restrict__ x, const float* __restrict__ pw_b,
    u16* __restrict__ xm)
{
  __shared__ __align__(16) u16 As[128*64];
  __shared__ __align__(16) u16 Bs[128*64];
  const int m0 = blockIdx.x * 128;
  const int n0 = blockIdx.y * 128;
  const int tid = threadIdx.x, w = tid>>6, l = tid&63;
  const f32x4 zf = {0.f,0.f,0.f,0.f};
  f32x4 acc[4][4];
  #pragma unroll
  for (int i=0;i<4;i++)
    #pragma unroll
    for (int j=0;j<4;j++) acc[i][j] = zf;

  for (int k0=0; k0<384; k0+=64) {
    #pragma unroll
    for (int i=0;i<4;i++){
      int ch = w*4+i;
      int row = ch*8 + (l>>3);
      gll16((const char*)t   + ((size_t)(m0+row)*384 + k0)*2 + (l&7)*16, (char*)As + ch*1024);
      gll16((const char*)pwb + ((size_t)(n0+row)*384 + k0)*2 + (l&7)*16, (char*)Bs + ch*1024);
    }
    __syncthreads();
    const int wr = (w>>1)*64, wc = (w&1)*64;
    #pragma unroll
    for (int kk=0; kk<64; kk+=32){
      bf16x8 a[4], bb[4];
      #pragma unroll
      for (int i=0;i<4;i++) a[i]  = *(const bf16x8*)&As[(wr + i*16 + (l&15))*64 + kk + (l>>4)*8];
      #pragma unroll
      for (int j=0;j<4;j++) bb[j] = *(const bf16x8*)&Bs[(wc + j*16 + (l&15))*64 + kk + (l>>4)*8];
      #pragma unroll
      for (int i=0;i<4;i++)
        #pragma unroll
        for (int j=0;j<4;j++)
          acc[i][j] = MFMA16(a[i], bb[j], acc[i][j]);
    }
    __syncthreads();
  }
  const int wr=(w>>1)*64, wc=(w&1)*64;
  #pragma unroll
  for (int j=0;j<4;j++){
    int n = n0 + wc + j*16 + (l&15);
    float bias = pw_b[n];
    #pragma unroll
    for (int i=0;i<4;i++)
      #pragma unroll
      for (int r=0;r<4;r++){
        int m = m0 + wr + i*16 + (l>>4)*4 + r;
        float v = acc[i][j][r] + x[(size_t)m*384 + n] + bias;
        xm[(size_t)m*384 + n] = f2bf(v);
      }
  }
}

// ---------------- k3: fused QKVG GEMM + activations + kv/ksum accum -------
// smem layout (40960 B):
//   main loop:  As = smem[0..8191] (128x64), Bs = smem[8192..20479] (192x64)
//   epilogue:   kT = smem[0..6527] ([48][136]), vT = smem[6528..13055]
//   reduce:     pbuf = (float*)smem, 4 waves x 2304 floats (36864 B)
__global__ __launch_bounds__(256) void k3_gemm_qkvg(
    const u16* __restrict__ xm, const u16* __restrict__ wpack,
    const float* __restrict__ bpack, const float* __restrict__ temperature,
    u16* __restrict__ qh, float* __restrict__ kvacc, float* __restrict__ ksumacc)
{
  __shared__ __align__(16) u16 smem[20480];
  u16* As = smem;
  u16* Bs = smem + 8192;
  const int m0 = blockIdx.x * 128;
  const int h  = blockIdx.y;
  const int tid = threadIdx.x, w = tid>>6, l = tid&63;
  const int lc = l & 15, hi = l >> 4;
  const f32x4 zf = {0.f,0.f,0.f,0.f};
  f32x4 acc[2][12];
  #pragma unroll
  for (int i=0;i<2;i++)
    #pragma unroll
    for (int j=0;j<12;j++) acc[i][j] = zf;

  for (int k0=0; k0<384; k0+=64){
    #pragma unroll
    for (int i=0;i<4;i++){
      int ch = w*4+i, row = ch*8 + (l>>3);
      gll16((const char*)xm + ((size_t)(m0+row)*384 + k0)*2 + (l&7)*16, (char*)As + ch*1024);
    }
    #pragma unroll
    for (int i=0;i<6;i++){
      int ch = w*6+i, row = ch*8 + (l>>3);
      gll16((const char*)wpack + ((size_t)(h*192+row)*384 + k0)*2 + (l&7)*16, (char*)Bs + ch*1024);
    }
    __syncthreads();
    const int rbase = w*32;
    #pragma unroll
    for (int kk=0; kk<64; kk+=32){
      bf16x8 a0 = *(const bf16x8*)&As[(rbase +      lc)*64 + kk + hi*8];
      bf16x8 a1 = *(const bf16x8*)&As[(rbase + 16 + lc)*64 + kk + hi*8];
      #pragma unroll
      for (int j=0;j<12;j++){
        bf16x8 bb = *(const bf16x8*)&Bs[(j*16 + lc)*64 + kk + hi*8];
        acc[0][j] = MFMA16(a0, bb, acc[0][j]);
        acc[1][j] = MFMA16(a1, bb, acc[1][j]);
      }
    }
    __syncthreads();
  }

  // ---- epilogue ----
  const float tq = temperature[h];
  const int b = m0 >> 12;
  const size_t bh = (size_t)b*8 + h;
  const int bb0 = h*192;
  float biasq[3], biask[3], biasv[3], biasg[3];
  #pragma unroll
  for (int j=0;j<3;j++){
    biasq[j] = bpack[bb0       + j*16 + lc];
    biask[j] = bpack[bb0 + 48  + j*16 + lc];
    biasv[j] = bpack[bb0 + 96  + j*16 + lc];
    biasg[j] = bpack[bb0 + 144 + j*16 + lc];
  }
  u16* kT = smem;          // [48][136]
  u16* vT = smem + 6528;   // [48][136]
  float ksp[3] = {0.f, 0.f, 0.f};

  #pragma unroll
  for (int i=0;i<2;i++){
    ushort4 kst[3], vst[3];
    #pragma unroll
    for (int r=0;r<4;r++){
      int m = m0 + w*32 + i*16 + hi*4 + r;
      int n = m & 4095;
      size_t rowq = (bh*4096 + n)*64;
      // q: temperature then phi
      float q0=(acc[i][0][r]+biasq[0])*tq;
      float q1=(acc[i][1][r]+biasq[1])*tq;
      float q2=(acc[i][2][r]+biasq[2])*tq;
      float mx = fmaxf(q0,fmaxf(q1,q2));
      mx = fmaxf(mx, __shfl_xor(mx,1,64));
      mx = fmaxf(mx, __shfl_xor(mx,2,64));
      mx = fmaxf(mx, __shfl_xor(mx,4,64));
      mx = fmaxf(mx, __shfl_xor(mx,8,64));
      qh[rowq +      lc] = f2bf(expf(q0-mx));
      qh[rowq + 16 + lc] = f2bf(expf(q1-mx));
      qh[rowq + 32 + lc] = f2bf(expf(q2-mx));
      qh[rowq + 48 + lc] = 0;                 // zero pad (K=64 for num GEMM)
      // k: phi
      float s0=acc[i][3][r]+biask[0];
      float s1=acc[i][4][r]+biask[1];
      float s2=acc[i][5][r]+biask[2];
      float mk = fmaxf(s0,fmaxf(s1,s2));
      mk = fmaxf(mk, __shfl_xor(mk,1,64));
      mk = fmaxf(mk, __shfl_xor(mk,2,64));
      mk = fmaxf(mk, __shfl_xor(mk,4,64));
      mk = fmaxf(mk, __shfl_xor(mk,8,64));
      float k0e = expf(s0-mk), k1e = expf(s1-mk), k2e = expf(s2-mk);
      ksp[0] += k0e; ksp[1] += k1e; ksp[2] += k2e;
      u16 kq0=f2bf(k0e), kq1=f2bf(k1e), kq2=f2bf(k2e);
      // v * sigmoid(g)
      u16 vq[3];
      #pragma unroll
      for (int j=0;j<3;j++){
        float vv = acc[i][6+j][r] + biasv[j];
        float gg = acc[i][9+j][r] + biasg[j];
        float sg = 1.f/(1.f + expf(-gg));
        vq[j] = f2bf(vv*sg);
      }
      if (r==0){ kst[0].x=kq0; kst[1].x=kq1; kst[2].x=kq2; vst[0].x=vq[0]; vst[1].x=vq[1]; vst[2].x=vq[2]; }
      if (r==1){ kst[0].y=kq0; kst[1].y=kq1; kst[2].y=kq2; vst[0].y=vq[0]; vst[1].y=vq[1]; vst[2].y=vq[2]; }
      if (r==2){ kst[0].z=kq0; kst[1].z=kq1; kst[2].z=kq2; vst[0].z=vq[0]; vst[1].z=vq[1]; vst[2].z=vq[2]; }
      if (r==3){ kst[0].w=kq0; kst[1].w=kq1; kst[2].w=kq2; vst[0].w=vq[0]; vst[1].w=vq[1]; vst[2].w=vq[2]; }
    }
    int mb = w*32 + i*16 + hi*4;
    #pragma unroll
    for (int j=0;j<3;j++){
      *(ushort4*)&kT[(j*16+lc)*136 + mb] = kst[j];
      *(ushort4*)&vT[(j*16+lc)*136 + mb] = vst[j];
    }
  }
  __syncthreads();

  // ---- kv partial via MFMA: wave w covers its own 32 tokens ----
  bf16x8 af[3], bfv[3];
  #pragma unroll
  for (int da=0;da<3;da++) af[da]  = *(const bf16x8*)&kT[(da*16+lc)*136 + w*32 + hi*8];
  #pragma unroll
  for (int eb=0;eb<3;eb++) bfv[eb] = *(const bf16x8*)&vT[(eb*16+lc)*136 + w*32 + hi*8];
  f32x4 a2[3][3];
  #pragma unroll
  for (int da=0;da<3;da++)
    #pragma unroll
    for (int eb=0;eb<3;eb++)
      a2[da][eb] = MFMA16(af[da], bfv[eb], zf);
  __syncthreads();
  float* pb = (float*)smem + w*2304;
  #pragma unroll
  for (int da=0;da<3;da++)
    #pragma unroll
    for (int eb=0;eb<3;eb++)
      #pragma unroll
      for (int rr=0;rr<4;rr++)
        pb[(da*16 + hi*4 + rr)*48 + eb*16 + lc] = a2[da][eb][rr];
  __syncthreads();
  float* p0 = (float*)smem;
  for (int u=tid; u<2304; u+=256){
    float s = p0[u] + p0[2304+u] + p0[4608+u] + p0[6912+u];
    atomicAdd(kvacc + bh*2304 + u, s);
  }
  // ---- ksum: reduce over hi groups, atomic per column ----
  #pragma unroll
  for (int j=0;j<3;j++){
    ksp[j] += __shfl_xor(ksp[j],16,64);
    ksp[j] += __shfl_xor(ksp[j],32,64);
  }
  if (hi==0){
    atomicAdd(ksumacc + bh*48 +      lc, ksp[0]);
    atomicAdd(ksumacc + bh*48 + 16 + lc, ksp[1]);
    atomicAdd(ksumacc + bh*48 + 32 + lc, ksp[2]);
  }
}

// ---------------- k5: kvacc/ksumacc -> kvp[e][d] bf16 (64x64, ksum row48) -
__global__ __launch_bounds__(256) void k5_red(
    const float* __restrict__ kvacc, const float* __restrict__ ksumacc,
    u16* __restrict__ kvp)
{
  int bh = blockIdx.x, tid = threadIdx.x;
  for (int u=tid; u<4096; u+=256){
    int e = u >> 6, d = u & 63;
    float v = 0.f;
    if (e < 48 && d < 48)       v = kvacc[(size_t)bh*2304 + d*48 + e];
    else if (e == 48 && d < 48) v = ksumacc[bh*48 + d];
    kvp[((size_t)bh*64 + e)*64 + d] = f2bf(v);
  }
}

// ---------------- k6: num/den -> a_hat bf16 [B,N,C] -----------------------
__global__ __launch_bounds__(256) void k6_num(
    const u16* __restrict__ qh, const u16* __restrict__ kvp, u16* __restrict__ ah)
{
  __shared__ __align__(16) u16 As[256*64]; // 32KB
  __shared__ __align__(16) u16 Bs[64*64];  // 8KB
  const int bh = blockIdx.x >> 4, nc = blockIdx.x & 15;
  const int tid = threadIdx.x, w = tid>>6, l = tid&63;
  const f32x4 zf = {0.f,0.f,0.f,0.f};
  const uint4* ga = (const uint4*)(qh + ((size_t)bh*4096 + nc*256)*64);
  #pragma unroll
  for (int it=0; it<8; ++it) ((uint4*)As)[it*256+tid] = ga[it*256+tid];
  const uint4* gb = (const uint4*)(kvp + (size_t)bh*4096);
  #pragma unroll
  for (int it=0; it<2; ++it) ((uint4*)Bs)[it*256+tid] = gb[it*256+tid];
  __syncthreads();
  f32x4 acc[4][4];
  #pragma unroll
  for (int i=0;i<4;i++)
    #pragma unroll
    for (int j=0;j<4;j++) acc[i][j] = zf;
  const int rbase = w*64;
  #pragma unroll
  for (int kk=0; kk<64; kk+=32){
    bf16x8 a[4], bb[4];
    #pragma unroll
    for (int i=0;i<4;i++) a[i]  = *(const bf16x8*)&As[(rbase + i*16 + (l&15))*64 + kk + (l>>4)*8];
    #pragma unroll
    for (int j=0;j<4;j++) bb[j] = *(const bf16x8*)&Bs[(j*16 + (l&15))*64 + kk + (l>>4)*8];
    #pragma unroll
    for (int i=0;i<4;i++)
      #pragma unroll
      for (int j=0;j<4;j++)
        acc[i][j] = MFMA16(a[i], bb[j], acc[i][j]);
  }
  const int b = bh >> 3, h = bh & 7;
  #pragma unroll
  for (int i=0;i<4;i++){
    #pragma unroll
    for (int r=0;r<4;r++){
      float den = __shfl(acc[i][3][r], l & 48, 64) + EPSF;  // col 48 = q . ksum
      float rd = 1.f/den;
      int n = nc*256 + rbase + i*16 + (l>>4)*4 + r;
      size_t ob = ((size_t)b*4096 + n)*384 + h*48;
      ah[ob +      (l&15)] = f2bf(acc[i][0][r]*rd);
      ah[ob + 16 + (l&15)] = f2bf(acc[i][1][r]*rd);
      ah[ob + 32 + (l&15)] = f2bf(acc[i][2][r]*rd);
    }
  }
}

// ---------------- k7: out = a_hat @ wo^T + bo (fp32) ----------------------
__global__ __launch_bounds__(256) void k7_gemm_out(
    const u16* __restrict__ ah, const u16* __restrict__ wob,
    const float* __restrict__ bo, float* __restrict__ out)
{
  __shared__ __align__(16) u16 As[128*64];
  __shared__ __align__(16) u16 Bs[128*64];
  const int m0 = blockIdx.x * 128;
  const int n0 = blockIdx.y * 128;
  const int tid = threadIdx.x, w = tid>>6, l = tid&63;
  const f32x4 zf = {0.f,0.f,0.f,0.f};
  f32x4 acc[4][4];
  #pragma unroll
  for (int i=0;i<4;i++)
    #pragma unroll
    for (int j=0;j<4;j++) acc[i][j] = zf;

  for (int k0=0; k0<384; k0+=64) {
    #pragma unroll
    for (int i=0;i<4;i++){
      int ch = w*4+i;
      int row = ch*8 + (l>>3);
      gll16((const char*)ah  + ((size_t)(m0+row)*384 + k0)*2 + (l&7)*16, (char*)As + ch*1024);
      gll16((const char*)wob + ((size_t)(n0+row)*384 + k0)*2 + (l&7)*16, (char*)Bs + ch*1024);
    }
    __syncthreads();
    const int wr = (w>>1)*64, wc = (w&1)*64;
    #pragma unroll
    for (int kk=0; kk<64; kk+=32){
      bf16x8 a[4], bb[4];
      #pragma unroll
      for (int i=0;i<4;i++) a[i]  = *(const bf16x8*)&As[(wr + i*16 + (l&15))*64 + kk + (l>>4)*8];
      #pragma unroll
      for (int j=0;j<4;j++) bb[j] = *(const bf16x8*)&Bs[(wc + j*16 + (l&15))*64 + kk + (l>>4)*8];
      #pragma unroll
      for (int i=0;i<4;i++)
        #pragma unroll
        for (int j=0;j<4;j++)
          acc[i][j] = MFMA16(a[i], bb[j], acc[i][j]);
    }
    __syncthreads();
  }
  const int wr=(w>>1)*64, wc=(w&1)*64;
  #pragma unroll
  for (int j=0;j<4;j++){
    int n = n0 + wc + j*16 + (l&15);
    float bias = bo[n];
    #pragma unroll
    for (int i=0;i<4;i++)
      #pragma unroll
      for (int r=0;r<4;r++){
        int m = m0 + wr + i*16 + (l>>4)*4 + r;
        out[(size_t)m*384 + n] = acc[i][j][r] + bias;
      }
  }
}

extern "C" void kernel_launch(void* const* d_in, const int* in_sizes, int n_in,
                              void* d_out, int out_size, void* d_ws, size_t ws_size,
                              hipStream_t stream)
{
  const float* x    = (const float*)d_in[0];
  const float* wq   = (const float*)d_in[1];
  const float* bq   = (const float*)d_in[2];
  const float* wk   = (const float*)d_in[3];
  const float* bk   = (const float*)d_in[4];
  const float* wv   = (const float*)d_in[5];
  const float* bv   = (const float*)d_in[6];
  const float* wg   = (const float*)d_in[7];
  const float* bg   = (const float*)d_in[8];
  const float* wo   = (const float*)d_in[9];
  const float* bo   = (const float*)d_in[10];
  const float* temp = (const float*)d_in[11];
  const float* dw_w = (const float*)d_in[12];
  const float* dw_b = (const float*)d_in[13];
  const float* pw_w = (const float*)d_in[14];
  const float* pw_b = (const float*)d_in[15];
  float* out = (float*)d_out;
  char* ws = (char*)d_ws;

  u16*   t       = (u16*)(ws + 0);            // 25165824 ; reused as a_hat
  u16*   xm      = (u16*)(ws + 25165824);     // 25165824
  u16*   qh      = (u16*)(ws + 50331648);     // 33554432  [B,H,N,64]
  u16*   wpack   = (u16*)(ws + 83886080);     // 1179648
  u16*   pwb     = (u16*)(ws + 85065728);     // 294912
  u16*   wob     = (u16*)(ws + 85360640);     // 294912
  float* bpack   = (float*)(ws + 85655552);   // 6144
  float* kvacc   = (float*)(ws + 85661696);   // 589824  [64][48][48] f32
  float* ksumacc = (float*)(ws + 86251520);   // 12288   [64][48] f32
  u16*   kvp     = (u16*)(ws + 86263808);     // 524288  [64][64][64] bf16

  k0_prep<<<4044, 256, 0, stream>>>(wq,bq,wk,bk,wv,bv,wg,bg,pw_w,wo,
                                    wpack,pwb,wob,bpack,kvacc,ksumacc);
  k1_dw<<<12288, 256, 0, stream>>>(x, dw_w, dw_b, t);
  k2_gemm_pw<<<dim3(256,3), 256, 0, stream>>>(t, pwb, x, pw_b, xm);
  k3_gemm_qkvg<<<dim3(256,8), 256, 0, stream>>>(xm, wpack, bpack, temp, qh, kvacc, ksumacc);
  k5_red<<<64, 256, 0, stream>>>(kvacc, ksumacc, kvp);
  k6_num<<<1024, 256, 0, stream>>>(qh, kvp, t /*a_hat*/);
  k7_gemm_out<<<dim3(256,3), 256, 0, stream>>>(t, wob, bo, out);
}

// Round 4
// 207.163 us; speedup vs baseline: 2.5256x; 1.4193x over previous
//
#include <hip/hip_runtime.h>
#include <math.h>

#define EPSF 1e-6f

typedef __attribute__((ext_vector_type(8))) short bf16x8;
typedef __attribute__((ext_vector_type(4))) float f32x4;
typedef unsigned short u16;
typedef unsigned int u32;

#define MFMA16(a,b,c) __builtin_amdgcn_mfma_f32_16x16x32_bf16((a),(b),(c),0,0,0)

__device__ __forceinline__ float bf2f(u16 u){
  union { u32 i; float f; } x; x.i = ((u32)u)<<16; return x.f;
}
__device__ __forceinline__ u16 f2bf(float f){
  u32 x = __builtin_bit_cast(u32, f);
  u32 r = (x + 0x7fffu + ((x >> 16) & 1u)) >> 16;
  return (u16)r;
}
__device__ __forceinline__ void gll16(const void* g, void* l){
  __builtin_amdgcn_global_load_lds(
      (const __attribute__((address_space(1))) u32*)g,
      (__attribute__((address_space(3))) u32*)l, 16, 0, 0);
}

// ---------------- k0: pack weights to bf16 + zero kv accumulators ---------
__global__ __launch_bounds__(256) void k0_prep(
    const float* __restrict__ wq, const float* __restrict__ bq,
    const float* __restrict__ wk, const float* __restrict__ bk,
    const float* __restrict__ wv, const float* __restrict__ bv,
    const float* __restrict__ wg, const float* __restrict__ bg,
    const float* __restrict__ pw_w, const float* __restrict__ wo,
    u16* __restrict__ wpack, u16* __restrict__ pwb, u16* __restrict__ wob,
    float* __restrict__ bpack, float* __restrict__ kvacc, float* __restrict__ ksumacc)
{
  int idx = blockIdx.x*256 + threadIdx.x;
  const int NW = 1536*384;
  if (idx < NW) {
    int r = idx / 384, c = idx - r*384;
    int h = r / 192, s = (r % 192)/48, d = r % 48;
    const float* w = (s==0)?wq:(s==1)?wk:(s==2)?wv:wg;
    wpack[idx] = f2bf(w[(h*48+d)*384 + c]);
    if (c==0){
      const float* b = (s==0)?bq:(s==1)?bk:(s==2)?bv:bg;
      bpack[r] = b[h*48+d];
    }
  } else if (idx < NW + 147456) {
    pwb[idx - NW] = f2bf(pw_w[idx - NW]);
  } else if (idx < NW + 2*147456) {
    wob[idx - NW - 147456] = f2bf(wo[idx - NW - 147456]);
  } else if (idx < NW + 2*147456 + 147456) {
    kvacc[idx - NW - 2*147456] = 0.f;
  } else if (idx < NW + 2*147456 + 147456 + 3072) {
    ksumacc[idx - NW - 2*147456 - 147456] = 0.f;
  }
}

// ---------------- k1: depthwise 3x3 conv (+dw_b) -> t bf16 ----------------
// 4 tokens x 4 channels per thread; weights fully in registers (9 x float4).
__global__ __launch_bounds__(256) void k1_dw(
    const float* __restrict__ x, const float* __restrict__ dw_w,
    const float* __restrict__ dw_b, u16* __restrict__ t)
{
  int idx = blockIdx.x*256 + threadIdx.x;   // 786432 threads
  int c4 = idx % 96; int rest = idx / 96;
  int jg = rest & 15; rest >>= 4;
  int i = rest & 63; int b = rest >> 6;
  int c0 = c4*4, j0 = jg*4;
  float wf[36];
  {
    const float4* wp = (const float4*)(dw_w + c0*9);
    #pragma unroll
    for (int k=0;k<9;k++){
      float4 v = wp[k];
      wf[4*k] = v.x; wf[4*k+1] = v.y; wf[4*k+2] = v.z; wf[4*k+3] = v.w;
    }
  }
  float4 bias = *(const float4*)(dw_b + c0);
  float acc[4][4];
  #pragma unroll
  for (int tk=0;tk<4;tk++){
    acc[tk][0]=bias.x; acc[tk][1]=bias.y; acc[tk][2]=bias.z; acc[tk][3]=bias.w;
  }
  const float* xb = x + ((size_t)b<<12)*384;
  #pragma unroll
  for (int di=-1; di<=1; ++di){
    int ii = i+di; if ((unsigned)ii >= 64u) continue;
    #pragma unroll
    for (int dj=-1; dj<=4; ++dj){
      int jj = j0+dj; if ((unsigned)jj >= 64u) continue;
      float4 xv = *(const float4*)(xb + (size_t)((ii<<6)+jj)*384 + c0);
      #pragma unroll
      for (int tk=0;tk<4;tk++){
        const int dd = dj - tk;            // column offset into 3x3 window
        if (dd < -1 || dd > 1) continue;   // compile-time prune after unroll
        const int tap = (di+1)*3 + (dd+1);
        acc[tk][0] = fmaf(xv.x, wf[0*9+tap], acc[tk][0]);
        acc[tk][1] = fmaf(xv.y, wf[1*9+tap], acc[tk][1]);
        acc[tk][2] = fmaf(xv.z, wf[2*9+tap], acc[tk][2]);
        acc[tk][3] = fmaf(xv.w, wf[3*9+tap], acc[tk][3]);
      }
    }
  }
  int mbase = (b<<12) + (i<<6) + j0;
  #pragma unroll
  for (int tk=0;tk<4;tk++){
    ushort4 o; o.x=f2bf(acc[tk][0]); o.y=f2bf(acc[tk][1]);
    o.z=f2bf(acc[tk][2]); o.w=f2bf(acc[tk][3]);
    *(ushort4*)(t + (size_t)(mbase+tk)*384 + c0) = o;
  }
}

// ---------------- k2: xm = bf16( x + t @ pw^T + pw_b ) --------------------
__global__ __launch_bounds__(256) void k2_gemm_pw(
    const u16* __restrict__ t, const u16* __restrict__ pwb,
    const float* __restrict__ x, const float* __restrict__ pw_b,
    u16* __restrict__ xm)
{
  __shared__ __align__(16) u16 As[128*64];
  __shared__ __align__(16) u16 Bs[128*64];
  const int m0 = blockIdx.x * 128;
  const int n0 = blockIdx.y * 128;
  const int tid = threadIdx.x, w = tid>>6, l = tid&63;
  const f32x4 zf = {0.f,0.f,0.f,0.f};
  f32x4 acc[4][4];
  #pragma unroll
  for (int i=0;i<4;i++)
    #pragma unroll
    for (int j=0;j<4;j++) acc[i][j] = zf;

  for (int k0=0; k0<384; k0+=64) {
    #pragma unroll
    for (int i=0;i<4;i++){
      int ch = w*4+i;
      int row = ch*8 + (l>>3);
      gll16((const char*)t   + ((size_t)(m0+row)*384 + k0)*2 + (l&7)*16, (char*)As + ch*1024);
      gll16((const char*)pwb + ((size_t)(n0+row)*384 + k0)*2 + (l&7)*16, (char*)Bs + ch*1024);
    }
    __syncthreads();
    const int wr = (w>>1)*64, wc = (w&1)*64;
    #pragma unroll
    for (int kk=0; kk<64; kk+=32){
      bf16x8 a[4], bb[4];
      #pragma unroll
      for (int i=0;i<4;i++) a[i]  = *(const bf16x8*)&As[(wr + i*16 + (l&15))*64 + kk + (l>>4)*8];
      #pragma unroll
      for (int j=0;j<4;j++) bb[j] = *(const bf16x8*)&Bs[(wc + j*16 + (l&15))*64 + kk + (l>>4)*8];
      #pragma unroll
      for (int i=0;i<4;i++)
        #pragma unroll
        for (int j=0;j<4;j++)
          acc[i][j] = MFMA16(a[i], bb[j], acc[i][j]);
    }
    __syncthreads();
  }
  const int wr=(w>>1)*64, wc=(w&1)*64;
  #pragma unroll
  for (int j=0;j<4;j++){
    int n = n0 + wc + j*16 + (l&15);
    float bias = pw_b[n];
    #pragma unroll
    for (int i=0;i<4;i++)
      #pragma unroll
      for (int r=0;r<4;r++){
        int m = m0 + wr + i*16 + (l>>4)*4 + r;
        float v = acc[i][j][r] + x[(size_t)m*384 + n] + bias;
        xm[(size_t)m*384 + n] = f2bf(v);
      }
  }
}

// ---------------- k3: fused QKVG GEMM + activations + kv/ksum accum -------
__global__ __launch_bounds__(256) void k3_gemm_qkvg(
    const u16* __restrict__ xm, const u16* __restrict__ wpack,
    const float* __restrict__ bpack, const float* __restrict__ temperature,
    u16* __restrict__ qh, float* __restrict__ kvacc, float* __restrict__ ksumacc)
{
  __shared__ __align__(16) u16 smem[20480];
  u16* As = smem;
  u16* Bs = smem + 8192;
  const int m0 = blockIdx.x * 128;
  const int h  = blockIdx.y;
  const int tid = threadIdx.x, w = tid>>6, l = tid&63;
  const int lc = l & 15, hi = l >> 4;
  const f32x4 zf = {0.f,0.f,0.f,0.f};
  f32x4 acc[2][12];
  #pragma unroll
  for (int i=0;i<2;i++)
    #pragma unroll
    for (int j=0;j<12;j++) acc[i][j] = zf;

  for (int k0=0; k0<384; k0+=64){
    #pragma unroll
    for (int i=0;i<4;i++){
      int ch = w*4+i, row = ch*8 + (l>>3);
      gll16((const char*)xm + ((size_t)(m0+row)*384 + k0)*2 + (l&7)*16, (char*)As + ch*1024);
    }
    #pragma unroll
    for (int i=0;i<6;i++){
      int ch = w*6+i, row = ch*8 + (l>>3);
      gll16((const char*)wpack + ((size_t)(h*192+row)*384 + k0)*2 + (l&7)*16, (char*)Bs + ch*1024);
    }
    __syncthreads();
    const int rbase = w*32;
    #pragma unroll
    for (int kk=0; kk<64; kk+=32){
      bf16x8 a0 = *(const bf16x8*)&As[(rbase +      lc)*64 + kk + hi*8];
      bf16x8 a1 = *(const bf16x8*)&As[(rbase + 16 + lc)*64 + kk + hi*8];
      #pragma unroll
      for (int j=0;j<12;j++){
        bf16x8 bb = *(const bf16x8*)&Bs[(j*16 + lc)*64 + kk + hi*8];
        acc[0][j] = MFMA16(a0, bb, acc[0][j]);
        acc[1][j] = MFMA16(a1, bb, acc[1][j]);
      }
    }
    __syncthreads();
  }

  // ---- epilogue ----
  const float tq = temperature[h];
  const int b = m0 >> 12;
  const size_t bh = (size_t)b*8 + h;
  const int bb0 = h*192;
  float biasq[3], biask[3], biasv[3], biasg[3];
  #pragma unroll
  for (int j=0;j<3;j++){
    biasq[j] = bpack[bb0       + j*16 + lc];
    biask[j] = bpack[bb0 + 48  + j*16 + lc];
    biasv[j] = bpack[bb0 + 96  + j*16 + lc];
    biasg[j] = bpack[bb0 + 144 + j*16 + lc];
  }
  u16* kT = smem;          // [48][136]
  u16* vT = smem + 6528;   // [48][136]
  float ksp[3] = {0.f, 0.f, 0.f};

  #pragma unroll
  for (int i=0;i<2;i++){
    ushort4 kst[3], vst[3];
    #pragma unroll
    for (int r=0;r<4;r++){
      int m = m0 + w*32 + i*16 + hi*4 + r;
      int n = m & 4095;
      size_t rowq = (bh*4096 + n)*64;
      float q0=(acc[i][0][r]+biasq[0])*tq;
      float q1=(acc[i][1][r]+biasq[1])*tq;
      float q2=(acc[i][2][r]+biasq[2])*tq;
      float mx = fmaxf(q0,fmaxf(q1,q2));
      mx = fmaxf(mx, __shfl_xor(mx,1,64));
      mx = fmaxf(mx, __shfl_xor(mx,2,64));
      mx = fmaxf(mx, __shfl_xor(mx,4,64));
      mx = fmaxf(mx, __shfl_xor(mx,8,64));
      qh[rowq +      lc] = f2bf(expf(q0-mx));
      qh[rowq + 16 + lc] = f2bf(expf(q1-mx));
      qh[rowq + 32 + lc] = f2bf(expf(q2-mx));
      qh[rowq + 48 + lc] = 0;
      float s0=acc[i][3][r]+biask[0];
      float s1=acc[i][4][r]+biask[1];
      float s2=acc[i][5][r]+biask[2];
      float mk = fmaxf(s0,fmaxf(s1,s2));
      mk = fmaxf(mk, __shfl_xor(mk,1,64));
      mk = fmaxf(mk, __shfl_xor(mk,2,64));
      mk = fmaxf(mk, __shfl_xor(mk,4,64));
      mk = fmaxf(mk, __shfl_xor(mk,8,64));
      float k0e = expf(s0-mk), k1e = expf(s1-mk), k2e = expf(s2-mk);
      ksp[0] += k0e; ksp[1] += k1e; ksp[2] += k2e;
      u16 kq0=f2bf(k0e), kq1=f2bf(k1e), kq2=f2bf(k2e);
      u16 vq[3];
      #pragma unroll
      for (int j=0;j<3;j++){
        float vv = acc[i][6+j][r] + biasv[j];
        float gg = acc[i][9+j][r] + biasg[j];
        float sg = 1.f/(1.f + expf(-gg));
        vq[j] = f2bf(vv*sg);
      }
      if (r==0){ kst[0].x=kq0; kst[1].x=kq1; kst[2].x=kq2; vst[0].x=vq[0]; vst[1].x=vq[1]; vst[2].x=vq[2]; }
      if (r==1){ kst[0].y=kq0; kst[1].y=kq1; kst[2].y=kq2; vst[0].y=vq[0]; vst[1].y=vq[1]; vst[2].y=vq[2]; }
      if (r==2){ kst[0].z=kq0; kst[1].z=kq1; kst[2].z=kq2; vst[0].z=vq[0]; vst[1].z=vq[1]; vst[2].z=vq[2]; }
      if (r==3){ kst[0].w=kq0; kst[1].w=kq1; kst[2].w=kq2; vst[0].w=vq[0]; vst[1].w=vq[1]; vst[2].w=vq[2]; }
    }
    int mb = w*32 + i*16 + hi*4;
    #pragma unroll
    for (int j=0;j<3;j++){
      *(ushort4*)&kT[(j*16+lc)*136 + mb] = kst[j];
      *(ushort4*)&vT[(j*16+lc)*136 + mb] = vst[j];
    }
  }
  __syncthreads();

  bf16x8 af[3], bfv[3];
  #pragma unroll
  for (int da=0;da<3;da++) af[da]  = *(const bf16x8*)&kT[(da*16+lc)*136 + w*32 + hi*8];
  #pragma unroll
  for (int eb=0;eb<3;eb++) bfv[eb] = *(const bf16x8*)&vT[(eb*16+lc)*136 + w*32 + hi*8];
  f32x4 a2[3][3];
  #pragma unroll
  for (int da=0;da<3;da++)
    #pragma unroll
    for (int eb=0;eb<3;eb++)
      a2[da][eb] = MFMA16(af[da], bfv[eb], zf);
  __syncthreads();
  float* pb = (float*)smem + w*2304;
  #pragma unroll
  for (int da=0;da<3;da++)
    #pragma unroll
    for (int eb=0;eb<3;eb++)
      #pragma unroll
      for (int rr=0;rr<4;rr++)
        pb[(da*16 + hi*4 + rr)*48 + eb*16 + lc] = a2[da][eb][rr];
  __syncthreads();
  float* p0 = (float*)smem;
  for (int u=tid; u<2304; u+=256){
    float s = p0[u] + p0[2304+u] + p0[4608+u] + p0[6912+u];
    atomicAdd(kvacc + bh*2304 + u, s);
  }
  #pragma unroll
  for (int j=0;j<3;j++){
    ksp[j] += __shfl_xor(ksp[j],16,64);
    ksp[j] += __shfl_xor(ksp[j],32,64);
  }
  if (hi==0){
    atomicAdd(ksumacc + bh*48 +      lc, ksp[0]);
    atomicAdd(ksumacc + bh*48 + 16 + lc, ksp[1]);
    atomicAdd(ksumacc + bh*48 + 32 + lc, ksp[2]);
  }
}

// ---------------- k5: kvacc/ksumacc -> kvp[e][d] bf16 (64x64, ksum row48) -
__global__ __launch_bounds__(256) void k5_red(
    const float* __restrict__ kvacc, const float* __restrict__ ksumacc,
    u16* __restrict__ kvp)
{
  int bh = blockIdx.x, tid = threadIdx.x;
  for (int u=tid; u<4096; u+=256){
    int e = u >> 6, d = u & 63;
    float v = 0.f;
    if (e < 48 && d < 48)       v = kvacc[(size_t)bh*2304 + d*48 + e];
    else if (e == 48 && d < 48) v = ksumacc[bh*48 + d];
    kvp[((size_t)bh*64 + e)*64 + d] = f2bf(v);
  }
}

// ---------------- k6: num/den -> a_hat bf16 [B,N,C] -----------------------
__global__ __launch_bounds__(256) void k6_num(
    const u16* __restrict__ qh, const u16* __restrict__ kvp, u16* __restrict__ ah)
{
  __shared__ __align__(16) u16 As[256*64]; // 32KB
  __shared__ __align__(16) u16 Bs[64*64];  // 8KB
  const int bh = blockIdx.x >> 4, nc = blockIdx.x & 15;
  const int tid = threadIdx.x, w = tid>>6, l = tid&63;
  const f32x4 zf = {0.f,0.f,0.f,0.f};
  const uint4* ga = (const uint4*)(qh + ((size_t)bh*4096 + nc*256)*64);
  #pragma unroll
  for (int it=0; it<8; ++it) ((uint4*)As)[it*256+tid] = ga[it*256+tid];
  const uint4* gb = (const uint4*)(kvp + (size_t)bh*4096);
  #pragma unroll
  for (int it=0; it<2; ++it) ((uint4*)Bs)[it*256+tid] = gb[it*256+tid];
  __syncthreads();
  f32x4 acc[4][4];
  #pragma unroll
  for (int i=0;i<4;i++)
    #pragma unroll
    for (int j=0;j<4;j++) acc[i][j] = zf;
  const int rbase = w*64;
  #pragma unroll
  for (int kk=0; kk<64; kk+=32){
    bf16x8 a[4], bb[4];
    #pragma unroll
    for (int i=0;i<4;i++) a[i]  = *(const bf16x8*)&As[(rbase + i*16 + (l&15))*64 + kk + (l>>4)*8];
    #pragma unroll
    for (int j=0;j<4;j++) bb[j] = *(const bf16x8*)&Bs[(j*16 + (l&15))*64 + kk + (l>>4)*8];
    #pragma unroll
    for (int i=0;i<4;i++)
      #pragma unroll
      for (int j=0;j<4;j++)
        acc[i][j] = MFMA16(a[i], bb[j], acc[i][j]);
  }
  const int b = bh >> 3, h = bh & 7;
  #pragma unroll
  for (int i=0;i<4;i++){
    #pragma unroll
    for (int r=0;r<4;r++){
      float den = __shfl(acc[i][3][r], l & 48, 64) + EPSF;
      float rd = 1.f/den;
      int n = nc*256 + rbase + i*16 + (l>>4)*4 + r;
      size_t ob = ((size_t)b*4096 + n)*384 + h*48;
      ah[ob +      (l&15)] = f2bf(acc[i][0][r]*rd);
      ah[ob + 16 + (l&15)] = f2bf(acc[i][1][r]*rd);
      ah[ob + 32 + (l&15)] = f2bf(acc[i][2][r]*rd);
    }
  }
}

// ---------------- k7: out = a_hat @ wo^T + bo (fp32) ----------------------
__global__ __launch_bounds__(256) void k7_gemm_out(
    const u16* __restrict__ ah, const u16* __restrict__ wob,
    const float* __restrict__ bo, float* __restrict__ out)
{
  __shared__ __align__(16) u16 As[128*64];
  __shared__ __align__(16) u16 Bs[128*64];
  const int m0 = blockIdx.x * 128;
  const int n0 = blockIdx.y * 128;
  const int tid = threadIdx.x, w = tid>>6, l = tid&63;
  const f32x4 zf = {0.f,0.f,0.f,0.f};
  f32x4 acc[4][4];
  #pragma unroll
  for (int i=0;i<4;i++)
    #pragma unroll
    for (int j=0;j<4;j++) acc[i][j] = zf;

  for (int k0=0; k0<384; k0+=64) {
    #pragma unroll
    for (int i=0;i<4;i++){
      int ch = w*4+i;
      int row = ch*8 + (l>>3);
      gll16((const char*)ah  + ((size_t)(m0+row)*384 + k0)*2 + (l&7)*16, (char*)As + ch*1024);
      gll16((const char*)wob + ((size_t)(n0+row)*384 + k0)*2 + (l&7)*16, (char*)Bs + ch*1024);
    }
    __syncthreads();
    const int wr = (w>>1)*64, wc = (w&1)*64;
    #pragma unroll
    for (int kk=0; kk<64; kk+=32){
      bf16x8 a[4], bb[4];
      #pragma unroll
      for (int i=0;i<4;i++) a[i]  = *(const bf16x8*)&As[(wr + i*16 + (l&15))*64 + kk + (l>>4)*8];
      #pragma unroll
      for (int j=0;j<4;j++) bb[j] = *(const bf16x8*)&Bs[(wc + j*16 + (l&15))*64 + kk + (l>>4)*8];
      #pragma unroll
      for (int i=0;i<4;i++)
        #pragma unroll
        for (int j=0;j<4;j++)
          acc[i][j] = MFMA16(a[i], bb[j], acc[i][j]);
    }
    __syncthreads();
  }
  const int wr=(w>>1)*64, wc=(w&1)*64;
  #pragma unroll
  for (int j=0;j<4;j++){
    int n = n0 + wc + j*16 + (l&15);
    float bias = bo[n];
    #pragma unroll
    for (int i=0;i<4;i++)
      #pragma unroll
      for (int r=0;r<4;r++){
        int m = m0 + wr + i*16 + (l>>4)*4 + r;
        out[(size_t)m*384 + n] = acc[i][j][r] + bias;
      }
  }
}

extern "C" void kernel_launch(void* const* d_in, const int* in_sizes, int n_in,
                              void* d_out, int out_size, void* d_ws, size_t ws_size,
                              hipStream_t stream)
{
  const float* x    = (const float*)d_in[0];
  const float* wq   = (const float*)d_in[1];
  const float* bq   = (const float*)d_in[2];
  const float* wk   = (const float*)d_in[3];
  const float* bk   = (const float*)d_in[4];
  const float* wv   = (const float*)d_in[5];
  const float* bv   = (const float*)d_in[6];
  const float* wg   = (const float*)d_in[7];
  const float* bg   = (const float*)d_in[8];
  const float* wo   = (const float*)d_in[9];
  const float* bo   = (const float*)d_in[10];
  const float* temp = (const float*)d_in[11];
  const float* dw_w = (const float*)d_in[12];
  const float* dw_b = (const float*)d_in[13];
  const float* pw_w = (const float*)d_in[14];
  const float* pw_b = (const float*)d_in[15];
  float* out = (float*)d_out;
  char* ws = (char*)d_ws;

  u16*   t       = (u16*)(ws + 0);            // 25165824 ; reused as a_hat
  u16*   xm      = (u16*)(ws + 25165824);     // 25165824
  u16*   qh      = (u16*)(ws + 50331648);     // 33554432  [B,H,N,64]
  u16*   wpack   = (u16*)(ws + 83886080);     // 1179648
  u16*   pwb     = (u16*)(ws + 85065728);     // 294912
  u16*   wob     = (u16*)(ws + 85360640);     // 294912
  float* bpack   = (float*)(ws + 85655552);   // 6144
  float* kvacc   = (float*)(ws + 85661696);   // 589824  [64][48][48] f32
  float* ksumacc = (float*)(ws + 86251520);   // 12288   [64][48] f32
  u16*   kvp     = (u16*)(ws + 86263808);     // 524288  [64][64][64] bf16

  k0_prep<<<4044, 256, 0, stream>>>(wq,bq,wk,bk,wv,bv,wg,bg,pw_w,wo,
                                    wpack,pwb,wob,bpack,kvacc,ksumacc);
  k1_dw<<<3072, 256, 0, stream>>>(x, dw_w, dw_b, t);
  k2_gemm_pw<<<dim3(256,3), 256, 0, stream>>>(t, pwb, x, pw_b, xm);
  k3_gemm_qkvg<<<dim3(256,8), 256, 0, stream>>>(xm, wpack, bpack, temp, qh, kvacc, ksumacc);
  k5_red<<<64, 256, 0, stream>>>(kvacc, ksumacc, kvp);
  k6_num<<<1024, 256, 0, stream>>>(qh, kvp, t /*a_hat*/);
  k7_gemm_out<<<dim3(256,3), 256, 0, stream>>>(t, wob, bo, out);
}